// Round 5
// baseline (198.125 us; speedup 1.0000x reference)
//
#include <hip/hip_runtime.h>
#include <stdint.h>

// RPN RoI proposal, 4-kernel pipeline (fills all 256 CUs for the data pass):
//  K1 (B*8 blocks): one pass over scores: per-slice 2048-bin LDS histogram
//     (atomic-flushed to global) + speculative gather of keys with
//     bin >= CONS(1984) into g_pairs[batch] (superset of exact top-2000;
//     E[count]=2812, cap 4096). Key = flipped_f32<<32 | bin<<20 |
//     (0xFFFFF - idx)  -> u64 descending sort == lax.top_k order.
//  K2 (B blocks): wave-shuffle suffix scan of exact histogram -> bsel,
//     tprime; fallback flag if speculation insufficient (bsel<CONS or
//     buffer overflow) -- probability ~0 but exactness guaranteed.
//  K3 (B blocks): fallback exact re-gather (bin>=bsel); normally returns
//     immediately.
//  K4 (B blocks): filter superset (bin>bsel -> pairs, ==bsel -> cand),
//     exact pivot, register bitonic sort of 2048 u64, decode boxes,
//     512x512 suppression tile (conflict-free layout), single-wave greedy
//     NMS reduce (early-exit at 300 kept), barrier-loop fallback, write
//     clipped [300,4].

#define PRE 2000
#define POST 300
#define TILE 512
#define IOU_THR 0.7f
#define EPSV 1e-8f
#define SORTN 2048
#define NBINS 2048
#define CANDCAP 512
#define PCAP 4096       // gathered-key capacity per batch
#define CONS 1984       // conservative speculative bin threshold
#define SL 8            // slices per batch in K1
#define KBUF 1536       // per-slice LDS key buffer

typedef unsigned long long u64;

__device__ __forceinline__ uint32_t flip_f32(uint32_t b) {
    // monotone map: float total order -> unsigned total order
    return b ^ ((uint32_t)((int32_t)b >> 31) | 0x80000000u);
}

__device__ __forceinline__ int bin_of(float s) {
    // monotone (non-injective) bucketing; uniform for U[0,1) scores
    int bn = (int)(s * 2048.0f);
    return min(max(bn, 0), NBINS - 1);
}

__device__ __forceinline__ u64 make_key(float s, int idx, int bn) {
    uint32_t ub = flip_f32(__float_as_uint(s));
    return ((u64)ub << 32) | ((uint32_t)bn << 20) |
           (uint32_t)(0xFFFFF - idx);   // idx < 2^20; lower idx sorts higher
}

__device__ __forceinline__ bool iou_gt(const float4& bi, float ai,
                                       const float4& bj, float aj) {
    // identical op order to reference: inter / (ai + aj - inter + EPS) > thr
    float yy1 = fmaxf(bi.x, bj.x);
    float xx1 = fmaxf(bi.y, bj.y);
    float yy2 = fminf(bi.z, bj.z);
    float xx2 = fminf(bi.w, bj.w);
    float inter = fmaxf(yy2 - yy1, 0.f) * fmaxf(xx2 - xx1, 0.f);
    float iou = inter / (ai + aj - inter + EPSV);
    return iou > IOU_THR;
}

// bitonic compare-keep: element index i, partner distance j, stage k.
__device__ __forceinline__ u64 cs_keep(u64 v, u64 pv, int i, int j, int k) {
    bool lower   = ((i & j) == 0);
    bool desc    = ((i & k) == 0);
    bool keepmax = (desc == lower);
    u64 mx = v > pv ? v : pv;
    u64 mn = v > pv ? pv : v;
    return keepmax ? mx : mn;
}

// ---------------- K1: histogram + speculative gather -----------------------
__global__ __launch_bounds__(256) void k1_hist_gather(
    const float4* __restrict__ score4,   // [B * N/4]
    uint32_t* __restrict__ g_hist,       // [B * 2048] (pre-zeroed)
    u64*      __restrict__ g_pairs,      // [B * PCAP]
    int*      __restrict__ g_cnt,        // [B] (pre-zeroed)
    int*      __restrict__ g_ovf,        // [B] (pre-zeroed)
    int N)
{
    const int blk = blockIdx.x;
    const int b   = blk / SL;
    const int s   = blk % SL;
    const int tid = threadIdx.x;
    const int F4PB = N >> 2;
    const int F4PS = (F4PB + SL - 1) / SL;

    __shared__ uint32_t hist[NBINS];
    __shared__ u64 keybuf[KBUF];
    __shared__ int kcnt, kbase;

    for (int i = tid; i < NBINS; i += 256) hist[i] = 0u;
    if (tid == 0) kcnt = 0;
    __syncthreads();

    const float4* src = score4 + (size_t)b * F4PB;
    const int n0 = s * F4PS, n1 = min(n0 + F4PS, F4PB);
    for (int n = n0 + tid; n < n1; n += 256) {
        float4 v = src[n];
        float sv[4] = {v.x, v.y, v.z, v.w};
#pragma unroll
        for (int c = 0; c < 4; ++c) {
            int bn = bin_of(sv[c]);
            atomicAdd(&hist[bn], 1u);
            if (bn >= CONS) {
                int q = atomicAdd(&kcnt, 1);
                if (q < KBUF) keybuf[q] = make_key(sv[c], 4 * n + c, bn);
            }
        }
    }
    __syncthreads();

    // flush exact histogram (integer atomics: order-independent)
    uint32_t* gh = g_hist + (size_t)b * NBINS;
    for (int i = tid; i < NBINS; i += 256) {
        uint32_t h = hist[i];
        if (h) atomicAdd(&gh[i], h);
    }
    // reserve contiguous range in g_pairs[b] and copy out
    int lc = min(kcnt, KBUF);
    if (tid == 0) {
        if (kcnt > KBUF) atomicOr(&g_ovf[b], 1);
        kbase = atomicAdd(&g_cnt[b], lc);
    }
    __syncthreads();
    int base = kbase;
    if (base + lc > PCAP) {
        if (tid == 0) atomicOr(&g_ovf[b], 1);
        lc = max(0, PCAP - base);
    }
    u64* gp = g_pairs + (size_t)b * PCAP + base;
    for (int i = tid; i < lc; i += 256) gp[i] = keybuf[i];
}

// ---------------- K2: exact bin select from histogram ----------------------
__global__ __launch_bounds__(1024) void k2_select(
    const uint32_t* __restrict__ g_hist,
    const int* __restrict__ g_cnt,
    const int* __restrict__ g_ovf,
    int2* __restrict__ g_sel,            // [B] (bsel, tprime)
    int*  __restrict__ g_flag)           // [B]
{
    const int b    = blockIdx.x;
    const int tid  = threadIdx.x;
    const int lane = tid & 63;
    const int wv   = tid >> 6;

    __shared__ uint32_t hist[NBINS];
    __shared__ uint32_t wtot[16];
    __shared__ int sh_bsel, sh_tprime;

    hist[tid]        = g_hist[(size_t)b * NBINS + tid];
    hist[tid + 1024] = g_hist[(size_t)b * NBINS + tid + 1024];
    __syncthreads();

    // wave-shuffle suffix scan; wave wv owns bins [wv*128, wv*128+128)
    const int i0 = wv * 128 + lane;
    const int i1 = i0 + 64;
    int h0 = (int)hist[i0];
    int h1 = (int)hist[i1];
    int s0 = h0, s1 = h1;
#pragma unroll
    for (int off = 1; off < 64; off <<= 1) {
        int t0 = __shfl_down(s0, off, 64);
        int t1 = __shfl_down(s1, off, 64);
        if (lane + off < 64) { s0 += t0; s1 += t1; }
    }
    int sum_h1 = __shfl(s1, 0, 64);
    if (lane == 0) wtot[wv] = (uint32_t)(__shfl(s0, 0, 64) + sum_h1);
    __syncthreads();
    int offtot = 0;
    for (int w2 = wv + 1; w2 < 16; ++w2) offtot += (int)wtot[w2];
    int S0 = s0 + sum_h1 + offtot;       // S(i0) = #{bin >= i0}
    int S1 = s1 + offtot;                // S(i1)
    if (S0 >= PRE && S0 - h0 < PRE) { sh_bsel = i0; sh_tprime = PRE - (S0 - h0); }
    if (S1 >= PRE && S1 - h1 < PRE) { sh_bsel = i1; sh_tprime = PRE - (S1 - h1); }
    __syncthreads();

    if (tid == 0) {
        g_sel[b] = make_int2(sh_bsel, sh_tprime);
        g_flag[b] = (sh_bsel < CONS) || (g_cnt[b] > PCAP) || g_ovf[b];
    }
}

// ---------------- K3: fallback exact gather (normally no-op) ---------------
__global__ __launch_bounds__(1024) void k3_fallback(
    const float4* __restrict__ score4,
    const int2* __restrict__ g_sel,
    const int*  __restrict__ g_flag,
    u64* __restrict__ g_pairs,
    int* __restrict__ g_cnt,
    int N)
{
    const int b = blockIdx.x;
    if (!g_flag[b]) return;
    const int tid  = threadIdx.x;
    const int bsel = g_sel[b].x;
    const int F4PB = N >> 2;
    if (tid == 0) g_cnt[b] = 0;
    __syncthreads();
    const float4* src = score4 + (size_t)b * F4PB;
    u64* gp = g_pairs + (size_t)b * PCAP;
    for (int n = tid; n < F4PB; n += 1024) {
        float4 v = src[n];
        float sv[4] = {v.x, v.y, v.z, v.w};
#pragma unroll
        for (int c = 0; c < 4; ++c) {
            int bn = bin_of(sv[c]);
            if (bn >= bsel) {
                int q = atomicAdd(&g_cnt[b], 1);
                if (q < PCAP) gp[q] = make_key(sv[c], 4 * n + c, bn);
            }
        }
    }
}

// ---------------- K4: filter + pivot + sort + decode + NMS + write ---------
__global__ __launch_bounds__(1024) void k4_sort_nms(
    const float4* __restrict__ deltas,   // [B*N] (dy,dx,dh,dw)
    const float4* __restrict__ anchors,  // [N]
    const u64*  __restrict__ g_pairs,
    const int*  __restrict__ g_cnt,
    const int2* __restrict__ g_sel,
    float4* __restrict__ out,            // [B*POST]
    int N)
{
    const int b    = blockIdx.x;
    const int tid  = threadIdx.x;
    const int lane = tid & 63;
    const int wv   = tid >> 6;

    __shared__ union PU {
        u64 pairs[SORTN];                // filter->sort->decode
        uint32_t supmat[16][TILE + 1];   // suppression tile (conflict-free)
    } p;
    __shared__ struct { float4 box[PRE]; float area[PRE]; } sbx;
    __shared__ u64 cand[CANDCAP];
    __shared__ uint32_t mask[63];        // fallback suppression mask
    __shared__ uint32_t kept[POST];
    __shared__ int sh_cnt, sh_nc, sh_kc;
    __shared__ uint32_t sh_pivot;

    if (tid == 0) { sh_cnt = 0; sh_nc = 0; }
    __syncthreads();

    // ---- filter superset: bin>bsel -> pairs, bin==bsel -> cand ----
    const int  nk     = min(g_cnt[b], PCAP);
    const int  bsel   = g_sel[b].x;
    const int  tprime = g_sel[b].y;
    const u64* gp     = g_pairs + (size_t)b * PCAP;
    for (int i = tid; i < nk; i += 1024) {
        u64 key = gp[i];
        int bn = (int)((key >> 20) & 0xFFFu);
        if (bn > bsel) {
            int q = atomicAdd(&sh_cnt, 1);       // = S(bsel+1) < PRE
            if (q < SORTN) p.pairs[q] = key;
        } else if (bn == bsel) {
            int t = atomicAdd(&sh_nc, 1);
            if (t < CANDCAP) cand[t] = key;
        }
    }
    __syncthreads();

    // ---- exact pivot among candidates (rank tprime, exact f32 bits) ----
    const int nc = min(sh_nc, CANDCAP);
    for (int i = tid; i < nc; i += 1024) {
        uint32_t vi = (uint32_t)(cand[i] >> 32);
        int g = 0, e = 0;
        for (int j = 0; j < nc; ++j) {
            uint32_t vj = (uint32_t)(cand[j] >> 32);
            g += (vj > vi);
            e += (vj == vi);
        }
        if (g < tprime && g + e >= tprime) sh_pivot = vi;  // unique value
    }
    __syncthreads();
    const uint32_t pivot = sh_pivot;
    for (int i = tid; i < nc; i += 1024) {
        uint32_t vi = (uint32_t)(cand[i] >> 32);
        if (vi >= pivot) {               // ties included; sort orders by idx
            int q = atomicAdd(&sh_cnt, 1);
            if (q < SORTN) p.pairs[q] = cand[i];
        }
    }
    __syncthreads();
    const int total = min(sh_cnt, SORTN);   // >= PRE by construction
    for (int q = total + tid; q < SORTN; q += 1024)
        p.pairs[q] = 0ull;                  // pad sorts below all real keys
    __syncthreads();

    // ---- bitonic sort in registers (2 elems/lane x 16 waves) ----
    {
        const int i0 = wv * 128 + lane;
        const int i1 = i0 + 64;
        u64 e0 = p.pairs[i0];
        u64 e1 = p.pairs[i1];
        for (int k = 2; k <= SORTN; k <<= 1) {
            for (int j = k >> 1; j > 0; j >>= 1) {
                if (j >= 128) {              // cross-wave via LDS
                    p.pairs[i0] = e0;
                    p.pairs[i1] = e1;
                    __syncthreads();
                    u64 p0 = p.pairs[i0 ^ j];
                    u64 p1 = p.pairs[i1 ^ j];
                    __syncthreads();
                    e0 = cs_keep(e0, p0, i0, j, k);
                    e1 = cs_keep(e1, p1, i1, j, k);
                } else if (j == 64) {        // partner is own other register
                    u64 a = e0, c = e1;
                    e0 = cs_keep(a, c, i0, 64, k);
                    e1 = cs_keep(c, a, i1, 64, k);
                } else {                     // intra-wave shuffle
                    e0 = cs_keep(e0, __shfl_xor(e0, j, 64), i0, j, k);
                    e1 = cs_keep(e1, __shfl_xor(e1, j, 64), i1, j, k);
                }
            }
        }
        p.pairs[i0] = e0;
        p.pairs[i1] = e1;
    }
    __syncthreads();

    // ---- decode top-2000 boxes into LDS ----
    const float4* dl = deltas + (size_t)b * N;
    for (int r = tid; r < PRE; r += 1024) {
        uint32_t idx = 0xFFFFFu - (uint32_t)(p.pairs[r] & 0xFFFFFull);
        float4 bx = make_float4(0.f, 0.f, 0.f, 0.f);
        float  ar = 0.f;
        if (idx < (uint32_t)N) {        // pad keys decode to idx >= N
            float4 d  = dl[idx];
            float4 an = anchors[idx];
            float ah  = an.z - an.x;
            float aw  = an.w - an.y;
            float acy = an.x + 0.5f * ah;
            float acx = an.y + 0.5f * aw;
            float h   = expf(d.z) * ah;
            float w   = expf(d.w) * aw;
            float cy  = d.x * ah + acy;
            float cx  = d.y * aw + acx;
            float y1  = cy - 0.5f * h;
            float x1  = cx - 0.5f * w;
            bx = make_float4(y1, x1, y1 + h, x1 + w);
            ar = fmaxf(bx.z - bx.x, 0.f) * fmaxf(bx.w - bx.y, 0.f);
        }
        sbx.box[r]  = bx;
        sbx.area[r] = ar;
    }
    for (int i = tid; i < 63; i += 1024) mask[i] = 0u;
    __syncthreads();   // pairs dead from here; supmat overlays

    // ---- 512x512 suppression tile, conflict-free layout ----
    for (int idx = tid; idx < TILE * 16; idx += 1024) {
        int i = idx & (TILE - 1);
        int w = idx >> 9;
        int jbase = w << 5;
        float4 bi = sbx.box[i];
        float  ai = sbx.area[i];
        uint32_t bits = 0u;
        if (jbase + 31 > i) {
#pragma unroll
            for (int c = 0; c < 32; ++c) {
                int j = jbase + c;
                if (j > i && iou_gt(bi, ai, sbx.box[j], sbx.area[j]))
                    bits |= (1u << c);
            }
        }
        p.supmat[w][i] = bits;
    }
    __syncthreads();

    // ---- single-wave sequential NMS reduce (no barriers) ----
    if (tid < 64) {
        uint32_t supw = 0u;
        int kc = 0, cur = 0;
        while (true) {
            uint32_t avail = (lane < 16) ? ~supw : 0u;
            int base = lane << 5;
            int rel  = cur - base;
            if (rel > 0) avail = (rel >= 32) ? 0u : (avail & (0xFFFFFFFFu << rel));
            int cand_i = avail ? (base + __ffs(avail) - 1) : 0x7FFFFFFF;
#pragma unroll
            for (int off = 32; off; off >>= 1)
                cand_i = min(cand_i, __shfl_xor(cand_i, off, 64));
            if (cand_i >= TILE) break;   // tile exhausted
            if (lane == 0) kept[kc] = (uint32_t)cand_i;
            ++kc;
            if (kc >= POST) break;       // keep flags monotone: final
            if (lane < 16) supw |= p.supmat[lane][cand_i];
            cur = cand_i + 1;
        }
        if (lane == 0) sh_kc = kc;
    }
    __syncthreads();
    int kc = sh_kc;

    // ---- fallback beyond the tile (not taken on this data) ----
    if (kc < POST) {
        for (int j = TILE + tid; j < PRE; j += 1024) {
            float4 bj = sbx.box[j];
            float  aj = sbx.area[j];
            bool sup = false;
            for (int k = 0; k < kc; ++k) {
                int i = (int)kept[k];
                if (iou_gt(sbx.box[i], sbx.area[i], bj, aj)) { sup = true; break; }
            }
            if (sup) atomicOr(&mask[j >> 5], 1u << (j & 31));
        }
        __syncthreads();
        int i = TILE;
        while (i < PRE) {
            while (i < PRE && ((mask[i >> 5] >> (i & 31)) & 1u)) ++i;
            if (i >= PRE) break;
            if (tid == 0) kept[kc] = (uint32_t)i;
            ++kc;
            if (kc >= POST) break;
            float4 bi = sbx.box[i];
            float  ai = sbx.area[i];
            for (int j = i + 1 + tid; j < PRE; j += 1024) {
                if (iou_gt(bi, ai, sbx.box[j], sbx.area[j]))
                    atomicOr(&mask[j >> 5], 1u << (j & 31));
            }
            ++i;
            __syncthreads();
        }
    }
    __syncthreads();

    // ---- write clipped output ----
    float4* ob = out + (size_t)b * POST;
    for (int r = tid; r < POST; r += 1024) {
        float4 o = make_float4(0.f, 0.f, 0.f, 0.f);
        if (r < kc) {
            float4 bx = sbx.box[kept[r]];
            o.x = fminf(fmaxf(bx.x, 0.f), 1.f);
            o.y = fminf(fmaxf(bx.y, 0.f), 1.f);
            o.z = fminf(fmaxf(bx.z, 0.f), 1.f);
            o.w = fminf(fmaxf(bx.w, 0.f), 1.f);
        }
        ob[r] = o;
    }
}

extern "C" void kernel_launch(void* const* d_in, const int* in_sizes, int n_in,
                              void* d_out, int out_size, void* d_ws, size_t ws_size,
                              hipStream_t stream) {
    const float4* deltas  = (const float4*)d_in[0];
    const float*  labels  = (const float*)d_in[1];
    const float4* anchors = (const float4*)d_in[2];
    const float4* score4  = (const float4*)labels;
    float4*       outp    = (float4*)d_out;
    const int N = in_sizes[2] / 4;      // 90000
    const int B = in_sizes[1] / N;      // 64

    // workspace layout (all 8B-aligned): pairs | hist | cnt | ovf | flag | sel
    char* ws = (char*)d_ws;
    u64*      g_pairs = (u64*)ws;                         // B*PCAP*8  = 2 MB
    uint32_t* g_hist  = (uint32_t*)(ws + (size_t)B * PCAP * 8);  // B*2048*4
    int*      g_cnt   = (int*)((char*)g_hist + (size_t)B * NBINS * 4);
    int*      g_ovf   = g_cnt + B;
    int*      g_flag  = g_ovf + B;
    int2*     g_sel   = (int2*)(g_flag + B);

    // zero hist + cnt + ovf + flag (one contiguous region)
    size_t zbytes = (size_t)B * NBINS * 4 + (size_t)B * 4 * 3;
    hipMemsetAsync((void*)g_hist, 0, zbytes, stream);

    k1_hist_gather<<<B * SL, 256, 0, stream>>>(score4, g_hist, g_pairs,
                                               g_cnt, g_ovf, N);
    k2_select<<<B, 1024, 0, stream>>>(g_hist, g_cnt, g_ovf, g_sel, g_flag);
    k3_fallback<<<B, 1024, 0, stream>>>(score4, g_sel, g_flag, g_pairs,
                                        g_cnt, N);
    k4_sort_nms<<<B, 1024, 0, stream>>>(deltas, anchors, g_pairs, g_cnt,
                                        g_sel, outp, N);
}

// Round 6
// 116.383 us; speedup vs baseline: 1.7024x; 1.7024x over previous
//
#include <hip/hip_runtime.h>
#include <stdint.h>

// RPN RoI proposal, 2-kernel pipeline:
//  K1 (B*8 blocks x 256): one pass over scores: per-slice 2048-bin LDS
//     histogram (atomic-flushed to global) + speculative gather of keys with
//     bin >= CONS(1984) into g_pairs[batch] (superset of exact top-2000,
//     E[count]=2812, cap 4096). Key = flipped_f32<<32 | bin<<20 |
//     (0xFFFFF - idx) -> u64 descending sort == lax.top_k order.
//  K4 (B blocks x 1024): histogram suffix-scan -> bsel/tprime; filter
//     superset (or exact in-block re-gather if speculation failed); exact
//     pivot; register bitonic sort of 2048 u64; decode boxes; row-major
//     512x512 suppression bit matrix [512][18]; CHUNKED greedy sweep:
//     64-index chunks resolved serially via v_readlane/scalar ops (no LDS
//     in the dependent chain), kept rows propagated to a 16-lane-distributed
//     removed mask in 4-wide batches; barrier-loop fallback beyond row 512;
//     write clipped [300,4].

#define PRE 2000
#define POST 300
#define TILE 512
#define IOU_THR 0.7f
#define EPSV 1e-8f
#define SORTN 2048
#define NBINS 2048
#define CANDCAP 512
#define PCAP 4096       // gathered-key capacity per batch
#define CONS 1984       // speculative bin threshold
#define SL 8            // K1 slices per batch
#define KBUF 1536       // K1 per-slice LDS key buffer
#define SSTR 18         // supmat row stride in words (8B-aligned u64 pairs)

typedef unsigned long long u64;

__device__ __forceinline__ uint32_t flip_f32(uint32_t b) {
    // monotone map: float total order -> unsigned total order
    return b ^ ((uint32_t)((int32_t)b >> 31) | 0x80000000u);
}

__device__ __forceinline__ int bin_of(float s) {
    int bn = (int)(s * 2048.0f);
    return min(max(bn, 0), NBINS - 1);
}

__device__ __forceinline__ u64 make_key(float s, int idx, int bn) {
    uint32_t ub = flip_f32(__float_as_uint(s));
    return ((u64)ub << 32) | ((uint32_t)bn << 20) |
           (uint32_t)(0xFFFFF - idx);   // idx < 2^20; lower idx sorts higher
}

__device__ __forceinline__ bool iou_gt(const float4& bi, float ai,
                                       const float4& bj, float aj) {
    // identical op order to reference
    float yy1 = fmaxf(bi.x, bj.x);
    float xx1 = fmaxf(bi.y, bj.y);
    float yy2 = fminf(bi.z, bj.z);
    float xx2 = fminf(bi.w, bj.w);
    float inter = fmaxf(yy2 - yy1, 0.f) * fmaxf(xx2 - xx1, 0.f);
    float iou = inter / (ai + aj - inter + EPSV);
    return iou > IOU_THR;
}

__device__ __forceinline__ u64 cs_keep(u64 v, u64 pv, int i, int j, int k) {
    bool lower   = ((i & j) == 0);
    bool desc    = ((i & k) == 0);
    bool keepmax = (desc == lower);
    u64 mx = v > pv ? v : pv;
    u64 mn = v > pv ? pv : v;
    return keepmax ? mx : mn;
}

// wave-aggregated LDS append; valid slot only where pred is true
__device__ __forceinline__ int wave_append(bool pred, int lane, int* cnt) {
    u64 bal = __ballot(pred);
    if (!bal) return -1;
    int tot = __popcll(bal);
    int fl  = __ffsll(bal) - 1;
    int base = 0;
    if (lane == fl) base = atomicAdd(cnt, tot);
    base = __shfl(base, fl, 64);
    return base + __popcll(bal & ((1ull << lane) - 1));
}

// ---------------- K1: histogram + speculative gather -----------------------
__global__ __launch_bounds__(256) void k1_hist_gather(
    const float4* __restrict__ score4,
    uint32_t* __restrict__ g_hist,       // [B*2048] pre-zeroed
    u64*      __restrict__ g_pairs,      // [B*PCAP]
    int*      __restrict__ g_cnt,        // [B] pre-zeroed
    int*      __restrict__ g_ovf,        // [B] pre-zeroed
    int N)
{
    const int blk = blockIdx.x;
    const int b   = blk / SL;
    const int s   = blk % SL;
    const int tid = threadIdx.x;
    const int F4PB = N >> 2;
    const int F4PS = (F4PB + SL - 1) / SL;

    __shared__ uint32_t hist[NBINS];
    __shared__ u64 keybuf[KBUF];
    __shared__ int kcnt, kbase;

    for (int i = tid; i < NBINS; i += 256) hist[i] = 0u;
    if (tid == 0) kcnt = 0;
    __syncthreads();

    const float4* src = score4 + (size_t)b * F4PB;
    const int n0 = s * F4PS, n1 = min(n0 + F4PS, F4PB);
    for (int n = n0 + tid; n < n1; n += 256) {
        float4 v = src[n];
        float sv[4] = {v.x, v.y, v.z, v.w};
#pragma unroll
        for (int c = 0; c < 4; ++c) {
            int bn = bin_of(sv[c]);
            atomicAdd(&hist[bn], 1u);
            if (bn >= CONS) {
                int q = atomicAdd(&kcnt, 1);
                if (q < KBUF) keybuf[q] = make_key(sv[c], 4 * n + c, bn);
            }
        }
    }
    __syncthreads();

    uint32_t* gh = g_hist + (size_t)b * NBINS;
    for (int i = tid; i < NBINS; i += 256) {
        uint32_t h = hist[i];
        if (h) atomicAdd(&gh[i], h);
    }
    int lc = min(kcnt, KBUF);
    if (tid == 0) {
        if (kcnt > KBUF) atomicOr(&g_ovf[b], 1);
        kbase = atomicAdd(&g_cnt[b], lc);
    }
    __syncthreads();
    int base = kbase;
    if (base + lc > PCAP) {
        if (tid == 0) atomicOr(&g_ovf[b], 1);
        lc = max(0, PCAP - base);
    }
    u64* gp = g_pairs + (size_t)b * PCAP + base;
    for (int i = tid; i < lc; i += 256) gp[i] = keybuf[i];
}

// ---------------- K4: scan+filter+pivot+sort+decode+NMS+write --------------
__global__ __launch_bounds__(1024) void k4_main(
    const float4* __restrict__ deltas,
    const float4* __restrict__ anchors,
    const float4* __restrict__ score4,
    const u64*  __restrict__ g_pairs,
    const int*  __restrict__ g_cnt,
    const int*  __restrict__ g_ovf,
    const uint32_t* __restrict__ g_hist,
    float4* __restrict__ out,
    int N)
{
    const int b    = blockIdx.x;
    const int tid  = threadIdx.x;
    const int lane = tid & 63;
    const int wv   = tid >> 6;

    __shared__ union PU {
        u64 pairs[SORTN];                 // also hosts hist at start
        uint32_t supmat[TILE][SSTR];      // row-major suppression matrix
    } p;
    __shared__ struct { float4 box[PRE]; float area[PRE]; } sbx;
    __shared__ u64 cand[CANDCAP];
    __shared__ uint32_t mask[63];
    __shared__ uint32_t kept[POST];
    __shared__ u64 sh_keepbits[TILE / 64];
    __shared__ uint32_t wtot[16];
    __shared__ int sh_bsel, sh_tprime, sh_cnt, sh_nc, sh_kc, sh_nq;
    __shared__ uint32_t sh_pivot;

    const int F4PB = N >> 2;

    // ---- histogram suffix scan (hist staged in pairs region) ----
    uint32_t* hist = (uint32_t*)p.pairs;
    hist[tid]        = g_hist[(size_t)b * NBINS + tid];
    hist[tid + 1024] = g_hist[(size_t)b * NBINS + tid + 1024];
    if (tid == 0) { sh_cnt = 0; sh_nc = 0; }
    __syncthreads();
    {
        const int i0 = wv * 128 + lane;
        const int i1 = i0 + 64;
        int h0 = (int)hist[i0];
        int h1 = (int)hist[i1];
        int s0 = h0, s1 = h1;
#pragma unroll
        for (int off = 1; off < 64; off <<= 1) {
            int t0 = __shfl_down(s0, off, 64);
            int t1 = __shfl_down(s1, off, 64);
            if (lane + off < 64) { s0 += t0; s1 += t1; }
        }
        int sum_h1 = __shfl(s1, 0, 64);
        if (lane == 0) wtot[wv] = (uint32_t)(__shfl(s0, 0, 64) + sum_h1);
        __syncthreads();
        int offtot = 0;
        for (int w2 = wv + 1; w2 < 16; ++w2) offtot += (int)wtot[w2];
        int S0 = s0 + sum_h1 + offtot;
        int S1 = s1 + offtot;
        if (S0 >= PRE && S0 - h0 < PRE) { sh_bsel = i0; sh_tprime = PRE - (S0 - h0); }
        if (S1 >= PRE && S1 - h1 < PRE) { sh_bsel = i1; sh_tprime = PRE - (S1 - h1); }
    }
    __syncthreads();
    const int bsel   = sh_bsel;
    const int tprime = sh_tprime;
    const bool flag  = (bsel < CONS) || (g_cnt[b] > PCAP) || g_ovf[b];
    __syncthreads();        // hist consumed; pairs region writable

    // ---- fill pairs/cand: from speculative superset, or exact re-gather ----
    if (!flag) {
        const int  nk = min(g_cnt[b], PCAP);
        const u64* gp = g_pairs + (size_t)b * PCAP;
        for (int i0 = 0; i0 < nk; i0 += 1024) {
            int i = i0 + tid;
            bool valid = (i < nk);
            u64 key = valid ? gp[i] : 0ull;
            int bn = (int)((key >> 20) & 0xFFFu);
            bool isP = valid && (bn > bsel);
            bool isC = valid && (bn == bsel);
            int sp = wave_append(isP, lane, &sh_cnt);
            if (isP) p.pairs[sp] = key;          // total = S(bsel+1) < PRE
            int sc = wave_append(isC, lane, &sh_nc);
            if (isC && sc < CANDCAP) cand[sc] = key;
        }
    } else {
        // exact fallback: full re-gather from scores (rare)
        const float4* src = score4 + (size_t)b * F4PB;
        for (int n = tid; n < F4PB; n += 1024) {
            float4 v = src[n];
            float sv[4] = {v.x, v.y, v.z, v.w};
#pragma unroll
            for (int c = 0; c < 4; ++c) {
                int bn = bin_of(sv[c]);
                if (bn >= bsel) {
                    u64 key = make_key(sv[c], 4 * n + c, bn);
                    if (bn > bsel) {
                        int q = atomicAdd(&sh_cnt, 1);
                        if (q < SORTN) p.pairs[q] = key;
                    } else {
                        int t = atomicAdd(&sh_nc, 1);
                        if (t < CANDCAP) cand[t] = key;
                    }
                }
            }
        }
    }
    __syncthreads();

    // ---- exact pivot among candidates (rank tprime, exact f32 bits) ----
    const int nc = min(sh_nc, CANDCAP);
    for (int i = tid; i < nc; i += 1024) {
        uint32_t vi = (uint32_t)(cand[i] >> 32);
        int g = 0, e = 0;
        for (int j = 0; j < nc; ++j) {
            uint32_t vj = (uint32_t)(cand[j] >> 32);
            g += (vj > vi);
            e += (vj == vi);
        }
        if (g < tprime && g + e >= tprime) sh_pivot = vi;
    }
    __syncthreads();
    const uint32_t pivot = sh_pivot;
    for (int i = tid; i < nc; i += 1024) {
        uint32_t vi = (uint32_t)(cand[i] >> 32);
        if (vi >= pivot) {
            int q = atomicAdd(&sh_cnt, 1);
            if (q < SORTN) p.pairs[q] = cand[i];
        }
    }
    __syncthreads();
    const int total = min(sh_cnt, SORTN);
    for (int q = total + tid; q < SORTN; q += 1024)
        p.pairs[q] = 0ull;
    __syncthreads();

    // ---- bitonic sort in registers (2 elems/lane x 16 waves) ----
    {
        const int i0 = wv * 128 + lane;
        const int i1 = i0 + 64;
        u64 e0 = p.pairs[i0];
        u64 e1 = p.pairs[i1];
        for (int k = 2; k <= SORTN; k <<= 1) {
            for (int j = k >> 1; j > 0; j >>= 1) {
                if (j >= 128) {
                    p.pairs[i0] = e0;
                    p.pairs[i1] = e1;
                    __syncthreads();
                    u64 p0 = p.pairs[i0 ^ j];
                    u64 p1 = p.pairs[i1 ^ j];
                    __syncthreads();
                    e0 = cs_keep(e0, p0, i0, j, k);
                    e1 = cs_keep(e1, p1, i1, j, k);
                } else if (j == 64) {
                    u64 a = e0, c = e1;
                    e0 = cs_keep(a, c, i0, 64, k);
                    e1 = cs_keep(c, a, i1, 64, k);
                } else {
                    e0 = cs_keep(e0, __shfl_xor(e0, j, 64), i0, j, k);
                    e1 = cs_keep(e1, __shfl_xor(e1, j, 64), i1, j, k);
                }
            }
        }
        p.pairs[i0] = e0;
        p.pairs[i1] = e1;
    }
    __syncthreads();

    // ---- decode top-2000 boxes into LDS ----
    const float4* dl = deltas + (size_t)b * N;
    for (int r = tid; r < PRE; r += 1024) {
        uint32_t idx = 0xFFFFFu - (uint32_t)(p.pairs[r] & 0xFFFFFull);
        float4 bx = make_float4(0.f, 0.f, 0.f, 0.f);
        float  ar = 0.f;
        if (idx < (uint32_t)N) {
            float4 d  = dl[idx];
            float4 an = anchors[idx];
            float ah  = an.z - an.x;
            float aw  = an.w - an.y;
            float acy = an.x + 0.5f * ah;
            float acx = an.y + 0.5f * aw;
            float h   = expf(d.z) * ah;
            float w   = expf(d.w) * aw;
            float cy  = d.x * ah + acy;
            float cx  = d.y * aw + acx;
            float y1  = cy - 0.5f * h;
            float x1  = cx - 0.5f * w;
            bx = make_float4(y1, x1, y1 + h, x1 + w);
            ar = fmaxf(bx.z - bx.x, 0.f) * fmaxf(bx.w - bx.y, 0.f);
        }
        sbx.box[r]  = bx;
        sbx.area[r] = ar;
    }
    for (int i = tid; i < 63; i += 1024) mask[i] = 0u;
    __syncthreads();   // pairs dead; supmat overlays

    // ---- 512x512 suppression matrix, row-major [i][w] ----
    for (int idx = tid; idx < TILE * 16; idx += 1024) {
        int i = idx & (TILE - 1);        // per-lane consecutive
        int w = idx >> 9;                // wave-uniform
        int jbase = w << 5;
        float4 bi = sbx.box[i];
        float  ai = sbx.area[i];
        uint32_t bits = 0u;
        if (jbase + 31 > i) {
#pragma unroll
            for (int c = 0; c < 32; ++c) {
                int j = jbase + c;
                if (j > i && iou_gt(bi, ai, sbx.box[j], sbx.area[j]))
                    bits |= (1u << c);
            }
        }
        p.supmat[i][w] = bits;
    }
    __syncthreads();

    // ---- chunked greedy sweep (wave 0): scalar resolve, no LDS chain ----
    if (tid < 64) {
        const uint32_t* sup = &p.supmat[0][0];
        uint32_t removedw = 0u;          // lanes 0..15: removed word w
        int kc = 0, nq = 0;
        for (int q = 0; q < TILE / 64; ++q) {
            const int cbase = q << 6;
            // per-lane: row (cbase+lane), in-chunk column words [2q, 2q+2)
            u64 rowchunk = *(const u64*)(sup + (size_t)(cbase + lane) * SSTR + 2 * q);
            uint32_t rcl = (uint32_t)rowchunk;
            uint32_t rch = (uint32_t)(rowchunk >> 32);
            uint32_t rlo = (uint32_t)__builtin_amdgcn_readlane((int)removedw, 2 * q);
            uint32_t rhi = (uint32_t)__builtin_amdgcn_readlane((int)removedw, 2 * q + 1);
            u64 avail = ~(((u64)rhi << 32) | rlo);   // not-yet-removed
            u64 keep = 0ull;
            while (avail) {                           // scalar greedy resolve
                int i = __ffsll(avail) - 1;
                keep |= (1ull << i);
                u64 row_i =
                    ((u64)(uint32_t)__builtin_amdgcn_readlane((int)rch, i) << 32) |
                    (uint32_t)__builtin_amdgcn_readlane((int)rcl, i);
                avail &= ~((1ull << i) | row_i);
            }
            if (lane == 0) sh_keepbits[q] = keep;
            kc += __popcll(keep);
            nq = q + 1;
            if (kc >= POST) break;
            // propagate kept rows into removedw, 4-wide batched reads
            u64 kb = keep;
            while (kb) {
                int c0 = __ffsll(kb) - 1; kb &= kb - 1;
                int c1 = c0, c2 = c0, c3 = c0;
                if (kb) { c1 = __ffsll(kb) - 1; kb &= kb - 1; }
                if (kb) { c2 = __ffsll(kb) - 1; kb &= kb - 1; }
                if (kb) { c3 = __ffsll(kb) - 1; kb &= kb - 1; }
                if (lane < 16) {
                    uint32_t a0 = sup[(size_t)(cbase + c0) * SSTR + lane];
                    uint32_t a1 = sup[(size_t)(cbase + c1) * SSTR + lane];
                    uint32_t a2 = sup[(size_t)(cbase + c2) * SSTR + lane];
                    uint32_t a3 = sup[(size_t)(cbase + c3) * SSTR + lane];
                    removedw |= (a0 | a1 | a2 | a3);
                }
            }
        }
        // compaction: kept[pos] in greedy order, capped at POST
        int base = 0;
        for (int q = 0; q < nq; ++q) {
            u64 kbq = sh_keepbits[q];
            int pos = base + __popcll(kbq & ((1ull << lane) - 1));
            if (((kbq >> lane) & 1ull) && pos < POST)
                kept[pos] = (uint32_t)(q * 64 + lane);
            base += __popcll(kbq);
        }
        if (lane == 0) { sh_kc = min(kc, POST); sh_nq = nq; }
    }
    __syncthreads();
    int kc = sh_kc;

    // ---- fallback beyond row 512 (not taken on this data) ----
    if (kc < POST) {
        for (int j = TILE + tid; j < PRE; j += 1024) {
            float4 bj = sbx.box[j];
            float  aj = sbx.area[j];
            bool sup = false;
            for (int k = 0; k < kc; ++k) {
                int i = (int)kept[k];
                if (iou_gt(sbx.box[i], sbx.area[i], bj, aj)) { sup = true; break; }
            }
            if (sup) atomicOr(&mask[j >> 5], 1u << (j & 31));
        }
        __syncthreads();
        int i = TILE;
        while (i < PRE) {
            while (i < PRE && ((mask[i >> 5] >> (i & 31)) & 1u)) ++i;
            if (i >= PRE) break;
            if (tid == 0) kept[kc] = (uint32_t)i;
            ++kc;
            if (kc >= POST) break;
            float4 bi = sbx.box[i];
            float  ai = sbx.area[i];
            for (int j = i + 1 + tid; j < PRE; j += 1024) {
                if (iou_gt(bi, ai, sbx.box[j], sbx.area[j]))
                    atomicOr(&mask[j >> 5], 1u << (j & 31));
            }
            ++i;
            __syncthreads();
        }
    }
    __syncthreads();

    // ---- write clipped output ----
    float4* ob = out + (size_t)b * POST;
    for (int r = tid; r < POST; r += 1024) {
        float4 o = make_float4(0.f, 0.f, 0.f, 0.f);
        if (r < kc) {
            float4 bx = sbx.box[kept[r]];
            o.x = fminf(fmaxf(bx.x, 0.f), 1.f);
            o.y = fminf(fmaxf(bx.y, 0.f), 1.f);
            o.z = fminf(fmaxf(bx.z, 0.f), 1.f);
            o.w = fminf(fmaxf(bx.w, 0.f), 1.f);
        }
        ob[r] = o;
    }
}

extern "C" void kernel_launch(void* const* d_in, const int* in_sizes, int n_in,
                              void* d_out, int out_size, void* d_ws, size_t ws_size,
                              hipStream_t stream) {
    const float4* deltas  = (const float4*)d_in[0];
    const float*  labels  = (const float*)d_in[1];
    const float4* anchors = (const float4*)d_in[2];
    const float4* score4  = (const float4*)labels;
    float4*       outp    = (float4*)d_out;
    const int N = in_sizes[2] / 4;      // 90000
    const int B = in_sizes[1] / N;      // 64

    // workspace: pairs | hist | cnt | ovf
    char* ws = (char*)d_ws;
    u64*      g_pairs = (u64*)ws;                                // B*PCAP*8
    uint32_t* g_hist  = (uint32_t*)(ws + (size_t)B * PCAP * 8);  // B*2048*4
    int*      g_cnt   = (int*)((char*)g_hist + (size_t)B * NBINS * 4);
    int*      g_ovf   = g_cnt + B;

    size_t zbytes = (size_t)B * NBINS * 4 + (size_t)B * 4 * 2;
    hipMemsetAsync((void*)g_hist, 0, zbytes, stream);

    k1_hist_gather<<<B * SL, 256, 0, stream>>>(score4, g_hist, g_pairs,
                                               g_cnt, g_ovf, N);
    k4_main<<<B, 1024, 0, stream>>>(deltas, anchors, score4, g_pairs,
                                    g_cnt, g_ovf, g_hist, outp, N);
}